// Round 11
// baseline (108.896 us; speedup 1.0000x reference)
//
#include <hip/hip_runtime.h>

typedef __attribute__((ext_vector_type(8))) short bf16x8;
typedef __attribute__((ext_vector_type(8))) unsigned short u16x8;
typedef __attribute__((ext_vector_type(4))) float f32x4;
typedef __attribute__((ext_vector_type(4))) int i32x4;
typedef __attribute__((ext_vector_type(4))) float float4v;

#define MFMA16(a, b, c) __builtin_amdgcn_mfma_f32_16x16x32_bf16((a), (b), (c), 0, 0, 0)

__device__ __forceinline__ unsigned short f2bf(float f) {
    unsigned u = __builtin_bit_cast(unsigned, f);
    u += 0x7fffu + ((u >> 16) & 1u);
    return (unsigned short)(u >> 16);
}
__device__ __forceinline__ float bf2f(unsigned short s) {
    unsigned u = ((unsigned)s) << 16;
    return __builtin_bit_cast(float, u);
}
__device__ __forceinline__ int pkbf(float a, float b) {
    return (int)f2bf(a) | ((int)f2bf(b) << 16);
}

// ---------------------------------------------------------------------------
// ws layout:
//   fp32 blk dump : ws[p*65536 + c*512 + m]            (64 p, 16.8 MB)
//   u16 region at wsh = (ushort*)(ws + 4194304):
//     Qhat: wsh[p*8192 + q*16 + d]                      (1 MB)
//     Khat: wsh[524288 + p*8192 + mk*16 + d]            (1 MB)
//     Vhat: wsh[1048576 + p*65536 + c*512 + m]          (8 MB)
// ---------------------------------------------------------------------------

// K1 fused:
//   blocks 0..511     : proj — per (p, stripe s of 64 keys): scattered diagonal
//                       read ONCE, dense fp32 dump + Qhat/Khat/Vhat via MFMA.
//   blocks 512..33279 : rocclr-style copy of ALL of x -> out: one-shot blocks,
//                       one float4 per thread, linear mapping, PLAIN cached
//                       loads/stores (mimics __amd_rocclr_copyBuffer's shape).
__global__ __launch_bounds__(256, 4) void fused_kernel(
    const float* __restrict__ x,
    const float* __restrict__ Wq, const float* __restrict__ bq,
    const float* __restrict__ Wk, const float* __restrict__ bk,
    const float* __restrict__ Wv,
    float* __restrict__ ws, float* __restrict__ out)
{
    __shared__ __attribute__((aligned(128))) char smem[36864];
    const int tid = threadIdx.x;
    const int bid = blockIdx.x;

    if (bid >= 512) {
        // ---------------- rocclr-shaped dense copy: 2^23 float4 ----------------
        const float4v* __restrict__ xin = (const float4v*)x;
        float4v* __restrict__ o4 = (float4v*)out;
        int u = (bid - 512) * 256 + tid;           // one f4 per thread, one-shot
        o4[u] = xin[u];
        return;
    }

    // ---------------- proj path (identical math to rounds 8-10) ----------------
    const int p = bid >> 3, s = bid & 7;
    const int ib = p >> 3, jb = p & 7;
    const int vbase = ib * 32768 + jb * 512 + ib * 8;
    const int lane = tid & 63, wv = tid >> 6;      // 4 waves
    const int g = lane >> 4, c15 = lane & 15;
    const f32x4 zacc = {0.f, 0.f, 0.f, 0.f};

    // weight fragments
    bf16x8 wqf[4], wkf[4], wvf2[2][4];
    #pragma unroll
    for (int ks = 0; ks < 4; ++ks) {
        const float4v* sq = (const float4v*)(Wq + c15 * 128 + ks * 32 + g * 8);
        const float4v* sk = (const float4v*)(Wk + c15 * 128 + ks * 32 + g * 8);
        float4v q0 = sq[0], q1 = sq[1];
        float4v k0 = sk[0], k1 = sk[1];
        #pragma unroll
        for (int e = 0; e < 4; ++e) {
            wqf[ks][e] = (short)f2bf(q0[e]); wqf[ks][4 + e] = (short)f2bf(q1[e]);
            wkf[ks][e] = (short)f2bf(k0[e]); wkf[ks][4 + e] = (short)f2bf(k1[e]);
        }
        #pragma unroll
        for (int cg = 0; cg < 2; ++cg) {
            const float4v* sv = (const float4v*)(Wv + (wv * 32 + cg * 16 + c15) * 128 + ks * 32 + g * 8);
            float4v v0 = sv[0], v1 = sv[1];
            #pragma unroll
            for (int e = 0; e < 4; ++e) {
                wvf2[cg][ks][e] = (short)f2bf(v0[e]); wvf2[cg][ks][4 + e] = (short)f2bf(v1[e]);
            }
        }
    }
    const float bqv = bq[c15], bkv = bk[c15];

    // stage stripe: scattered reads once; dense fp32 dump; LDS transpose.
    float* blkws = ws + p * 65536;
    #pragma unroll
    for (int k = 0; k < 2; ++k) {
        int pi = k * 256 + tid;
        int cpair = pi >> 3, m8 = pi & 7;
        int c0 = cpair * 2;
        int mg = s * 64 + m8 * 8;
        int vox = s * 4096 + m8 * 64;
        const float* src0 = x + c0 * 262144 + vbase + vox;
        float4v a0 = *(const float4v*)(src0);
        float4v a1 = *(const float4v*)(src0 + 4);
        float4v b0 = *(const float4v*)(src0 + 262144);
        float4v b1 = *(const float4v*)(src0 + 262144 + 4);
        *(float4v*)(blkws + c0 * 512 + mg)           = a0;
        *(float4v*)(blkws + c0 * 512 + mg + 4)       = a1;
        *(float4v*)(blkws + c0 * 512 + 512 + mg)     = b0;
        *(float4v*)(blkws + c0 * 512 + 512 + mg + 4) = b1;
        int ml = m8 * 8;
        #pragma unroll
        for (int j = 0; j < 4; ++j) {
            int m = ml + j;
            unsigned v = (unsigned)f2bf(a0[j]) | ((unsigned)f2bf(b0[j]) << 16);
            *(unsigned*)(smem + ((m * 256 + 4 * cpair) ^ (((m >> 2) & 7) << 4))) = v;
        }
        #pragma unroll
        for (int j = 0; j < 4; ++j) {
            int m = ml + 4 + j;
            unsigned v = (unsigned)f2bf(a1[j]) | ((unsigned)f2bf(b1[j]) << 16);
            *(unsigned*)(smem + ((m * 256 + 4 * cpair) ^ (((m >> 2) & 7) << 4))) = v;
        }
    }
    __syncthreads();

    // Qhat + Khat for the stripe's 64 rows
    {
        f32x4 qa = zacc, kacc = zacc;
        int mrow = wv * 16 + c15;
        int sw = ((mrow >> 2) & 7) << 4;
        #pragma unroll
        for (int ks = 0; ks < 4; ++ks) {
            bf16x8 af = *(const bf16x8*)(smem + ((mrow * 256 + ks * 64 + g * 16) ^ sw));
            qa = MFMA16(af, wqf[ks], qa);
            kacc = MFMA16(af, wkf[ks], kacc);
        }
        #pragma unroll
        for (int r = 0; r < 4; ++r) {
            int row = wv * 16 + g * 4 + r;
            *(unsigned short*)(smem + 16384 + row * 32 + 2 * c15) = f2bf(qa[r] + bqv);
            *(unsigned short*)(smem + 18432 + row * 32 + 2 * c15) = f2bf(kacc[r] + bkv);
        }
    }

    // Vhat: wave wv owns channels [wv*32, wv*32+32)
    f32x4 vacc[2][4];
    #pragma unroll
    for (int cg = 0; cg < 2; ++cg)
        #pragma unroll
        for (int mt = 0; mt < 4; ++mt) {
            vacc[cg][mt] = zacc;
            int mrow = mt * 16 + c15;
            int sw = ((mrow >> 2) & 7) << 4;
            #pragma unroll
            for (int ks = 0; ks < 4; ++ks) {
                bf16x8 bf = *(const bf16x8*)(smem + ((mrow * 256 + ks * 64 + g * 16) ^ sw));
                vacc[cg][mt] = MFMA16(wvf2[cg][ks], bf, vacc[cg][mt]);
            }
        }
    char* vt = smem + 20480 + wv * 4096;
    #pragma unroll
    for (int cg = 0; cg < 2; ++cg)
        #pragma unroll
        for (int mt = 0; mt < 4; ++mt)
            #pragma unroll
            for (int r = 0; r < 4; ++r)
                *(unsigned short*)(vt + (cg * 16 + g * 4 + r) * 128 + 2 * (mt * 16 + c15))
                    = f2bf(vacc[cg][mt][r]);

    unsigned short* wsh = (unsigned short*)(ws + 4194304);
    unsigned short* wsv = wsh + 1048576 + p * 65536 + s * 64;
    #pragma unroll
    for (int i = 0; i < 4; ++i) {
        int lb = i * 1024 + lane * 16;
        u16x8 vv = *(const u16x8*)(vt + lb);
        int c_local = lb >> 7;
        int moff = (lane & 7) * 8;
        *(u16x8*)(wsv + (wv * 32 + c_local) * 512 + moff) = vv;
    }
    __syncthreads();
    unsigned short* wsq = wsh + p * 8192 + s * 1024;
    unsigned short* wsk = wsh + 524288 + p * 8192 + s * 1024;
    long long qd = *(const long long*)(smem + 16384 + tid * 8);
    long long kd = *(const long long*)(smem + 18432 + tid * 8);
    *(long long*)(wsq + tid * 4) = qd;
    *(long long*)(wsk + tid * 4) = kd;
}

// K2: attention from dense precomputed Qhat/Khat/Vhat. 4 wgs per p.
#define KOFF 131072
#define LOFF 147456

__global__ __launch_bounds__(512, 2) void attn_kernel(
    const float* __restrict__ ws,
    const float* __restrict__ bv, const float* __restrict__ gamma,
    float* __restrict__ out)
{
    __shared__ __attribute__((aligned(128))) char smem[147968];
    const int tid = threadIdx.x;
    const int bid = blockIdx.x;
    const int p  = ((bid & 7) << 3) | (bid >> 5);
    const int qq = (bid >> 3) & 3;
    const int ib = p >> 3, jb = p & 7;
    const int vbase = ib * 32768 + jb * 512 + ib * 8;
    const int lane = tid & 63, wv = tid >> 6;
    const int g = lane >> 4, c15 = lane & 15;
    const f32x4 zacc = {0.f, 0.f, 0.f, 0.f};
    const bf16x8 zfrag = (bf16x8)(short)0;

    const unsigned short* wsh = (const unsigned short*)(ws + 4194304);
    const unsigned short* wsq = wsh + p * 8192;
    const unsigned short* wsk = wsh + 524288 + p * 8192;
    const unsigned short* wsv = wsh + 1048576 + p * 65536;

    // stage Vhat -> LDS swizzled (dense b128 both sides; L2/L3-hot from K1)
    #pragma unroll
    for (int i = 0; i < 16; ++i) {
        int li = (i * 512 + tid) * 8;
        int c = li >> 9, m = li & 511;
        u16x8 v = *(const u16x8*)(wsv + li);
        *(u16x8*)(smem + c * 1024 + ((2 * m) ^ ((c & 7) << 4))) = v;
    }
    // stage Khat (16 KB linear)
    #pragma unroll
    for (int i = 0; i < 2; ++i) {
        int t8 = i * 512 + tid;
        u16x8 v = *(const u16x8*)(wsk + t8 * 8);
        *(u16x8*)(smem + KOFF + t8 * 16) = v;
    }
    bf16x8 qf = zfrag;
    if (g < 2) qf = *(const bf16x8*)(wsq + (qq * 128 + wv * 16 + c15) * 16 + g * 8);
    __syncthreads();

    // key-tile loop
    f32x4 o[8];
    #pragma unroll
    for (int ci = 0; ci < 8; ++ci) o[ci] = zacc;
    float lsum = 0.f;

    for (int kt = 0; kt < 16; ++kt) {
        int mk0 = kt * 32;
        bf16x8 ka[2];
        #pragma unroll
        for (int ki = 0; ki < 2; ++ki) {
            bf16x8 v = zfrag;
            if (g < 2) v = *(const bf16x8*)(smem + KOFF + (mk0 + ki * 16 + c15) * 32 + g * 16);
            ka[ki] = v;
        }

        f32x4 s0 = MFMA16(ka[0], qf, zacc);
        f32x4 s1 = MFMA16(ka[1], qf, zacc);
        float e00 = __expf(s0[0]), e01 = __expf(s0[1]), e02 = __expf(s0[2]), e03 = __expf(s0[3]);
        float e10 = __expf(s1[0]), e11 = __expf(s1[1]), e12 = __expf(s1[2]), e13 = __expf(s1[3]);
        lsum += (e00 + e01) + (e02 + e03) + ((e10 + e11) + (e12 + e13));
        int wA0 = pkbf(e00, e01), wB0 = pkbf(e02, e03);
        int wA1 = pkbf(e10, e11), wB1 = pkbf(e12, e13);
        int src1 = ((2 * g) & 3) * 16 + c15;
        int src2 = ((2 * g + 1) & 3) * 16 + c15;
        int sA0a = __shfl(wA0, src1, 64), sA1a = __shfl(wA1, src1, 64);
        int sB0a = __shfl(wB0, src1, 64), sB1a = __shfl(wB1, src1, 64);
        int sA0b = __shfl(wA0, src2, 64), sA1b = __shfl(wA1, src2, 64);
        int sB0b = __shfl(wB0, src2, 64), sB1b = __shfl(wB1, src2, 64);
        bool k1 = (g >= 2);
        i32x4 uu = { k1 ? sA1a : sA0a, k1 ? sB1a : sB0a,
                     k1 ? sA1b : sA0b, k1 ? sB1b : sB0b };
        bf16x8 pa = __builtin_bit_cast(bf16x8, uu);

        #pragma unroll
        for (int ci = 0; ci < 8; ++ci) {
            int c = ci * 16 + c15;
            bf16x8 vb = *(const bf16x8*)(smem + c * 1024 + ((2 * mk0 + 16 * g) ^ ((c & 7) << 4)));
            o[ci] = MFMA16(pa, vb, o[ci]);
        }
    }

    // softmax denominators
    {
        float l = lsum;
        l += __shfl_xor(l, 16, 64);
        l += __shfl_xor(l, 32, 64);
        if (g == 0)
            *(float*)(smem + LOFF + (wv * 16 + c15) * 4) = l;
    }

    __syncthreads();

    #pragma unroll
    for (int ci = 0; ci < 8; ++ci)
        #pragma unroll
        for (int r = 0; r < 4; ++r) {
            int nql = wv * 16 + g * 4 + r;
            int c = ci * 16 + c15;
            *(unsigned short*)(smem + c * 256 + ((2 * nql) ^ ((c & 7) << 4))) = f2bf(o[ci][r]);
        }
    __syncthreads();

    // epilogue: out = gamma*(O/l + bv) + x ; residual dense from ws blk dump.
    // Scattered 32 B-granule stores stay NON-TEMPORAL (partial-line writes).
    float gma = gamma[0];
    int q128 = tid & 127;
    int cb = tid >> 7;
    float invl = 1.0f / *(const float*)(smem + LOFF + q128 * 4);
    int nq = qq * 128 + q128;
    int vox = ((nq >> 6) << 12) + (((nq >> 3) & 7) << 6) + (nq & 7);
    int go = vbase + vox;
    const float* blkws = ws + p * 65536 + nq;
    #pragma unroll
    for (int b = 0; b < 4; ++b) {
        float xv[8];
        #pragma unroll
        for (int j = 0; j < 8; ++j) {
            int c = cb * 32 + b * 8 + j;
            xv[j] = blkws[c * 512];
        }
        #pragma unroll
        for (int j = 0; j < 8; ++j) {
            int c = cb * 32 + b * 8 + j;
            float ov = bf2f(*(const unsigned short*)(smem + c * 256 + ((2 * q128) ^ ((c & 7) << 4))));
            float res = gma * (ov * invl + bv[c]) + xv[j];
            __builtin_nontemporal_store(res, out + c * 262144 + go);
        }
    }
}

extern "C" void kernel_launch(void* const* d_in, const int* in_sizes, int n_in,
                              void* d_out, int out_size, void* d_ws, size_t ws_size,
                              hipStream_t stream) {
    const float* x     = (const float*)d_in[0];
    const float* Wq    = (const float*)d_in[1];
    const float* bq    = (const float*)d_in[2];
    const float* Wk    = (const float*)d_in[3];
    const float* bk    = (const float*)d_in[4];
    const float* Wv    = (const float*)d_in[5];
    const float* bv    = (const float*)d_in[6];
    const float* gamma = (const float*)d_in[7];
    float* out = (float*)d_out;
    float* ws  = (float*)d_ws;
    (void)in_sizes; (void)n_in; (void)out_size; (void)ws_size;

    // K1: proj (blocks 0..511) + rocclr-shaped dense copy (blocks 512..33279).
    fused_kernel<<<dim3(33280), dim3(256), 0, stream>>>(x, Wq, bq, Wk, bk, Wv, ws, out);
    // K2: attention from dense ws; overwrites diagonal of out (nt stores).
    attn_kernel<<<dim3(256), dim3(512), 0, stream>>>(ws, bv, gamma, out);
}

// Round 12
// 101.631 us; speedup vs baseline: 1.0715x; 1.0715x over previous
//
#include <hip/hip_runtime.h>

typedef __attribute__((ext_vector_type(8))) short bf16x8;
typedef __attribute__((ext_vector_type(4))) float f32x4;
typedef __attribute__((ext_vector_type(4))) int i32x4;
typedef __attribute__((ext_vector_type(4))) float float4v;

#define MFMA16(a, b, c) __builtin_amdgcn_mfma_f32_16x16x32_bf16((a), (b), (c), 0, 0, 0)

__device__ __forceinline__ unsigned short f2bf(float f) {
    unsigned u = __builtin_bit_cast(unsigned, f);
    u += 0x7fffu + ((u >> 16) & 1u);
    return (unsigned short)(u >> 16);
}
__device__ __forceinline__ float bf2f(unsigned short s) {
    unsigned u = ((unsigned)s) << 16;
    return __builtin_bit_cast(float, u);
}
__device__ __forceinline__ int pkbf(float a, float b) {
    return (int)f2bf(a) | ((int)f2bf(b) << 16);
}

// LDS map (bytes), total 147968:
//   [0, 131072)       blk^T bf16 [m=512][c=128], byte = (m*256 + 2c) ^ (((m>>2)&7)<<4)
//                     then (chunk ck): Vhat bf16, byte = ck*32768 + c*256 + (2*(mk&127) ^ ((c&7)<<4))
//                     then (after P4): O bf16 [c=128][nql=128], byte = c*256 + (2*nql ^ ((c&7)<<4))
//   [131072, 147456)  per-wave qhat scratch (wv*2048), then Khat bf16 [mk=512][d=16]: mk*32 + 2d
//   [147456, 147968)  l[128] f32 softmax denominators (wg-local queries)
#define KOFF 131072
#define LOFF 147456

// ---------------------------------------------------------------------------
// Diagonal-block attention, 4 workgroups per block p (256 wgs total),
// XCD-co-located (bid&7 = XCD). Runs AFTER the SDMA memcpy (out = x).
// Staging reads x (immutable — safe across wgs). Epilogue is an in-place
// RMW on `out`: each thread reads ONLY the elements it alone writes
// (race-free), and those lines are L2/L3-hot from the memcpy's writes.
// ---------------------------------------------------------------------------
__global__ __launch_bounds__(512, 2) void battn_kernel(
    const float* __restrict__ x,
    const float* __restrict__ Wq, const float* __restrict__ bq,
    const float* __restrict__ Wk, const float* __restrict__ bk,
    const float* __restrict__ Wv, const float* __restrict__ bv,
    const float* __restrict__ gamma, float* __restrict__ out)
{
    __shared__ __attribute__((aligned(128))) char smem[147968];
    const int tid = threadIdx.x;
    const int bid = blockIdx.x;
    const int p  = ((bid & 7) << 3) | (bid >> 5);   // 64 blocks, 4 wgs/p per XCD
    const int qq = (bid >> 3) & 3;                  // query quarter
    const int ib = p >> 3, jb = p & 7;
    const int vbase = ib * 8 * 4096 + jb * 8 * 64 + ib * 8;
    const int lane = tid & 63, wv = tid >> 6;
    const int g = lane >> 4, c15 = lane & 15;

    // phase 0: stage FULL x block -> blk^T bf16 (swizzled), batched 8-deep.
    #pragma unroll
    for (int b = 0; b < 4; ++b) {
        float4v t[8];
        #pragma unroll
        for (int j = 0; j < 8; ++j) {
            int ch = (b * 8 + j) * 512 + tid;
            int c = ch >> 7;
            int m = (ch & 127) * 4;
            int vox = ((m >> 6) << 12) + (((m >> 3) & 7) << 6) + (m & 7);
            t[j] = *(const float4v*)(x + c * 262144 + vbase + vox);
        }
        #pragma unroll
        for (int j = 0; j < 8; ++j) {
            int ch = (b * 8 + j) * 512 + tid;
            int c = ch >> 7;
            int m = (ch & 127) * 4;
            char* bp = smem + ((m * 256 + 2 * c) ^ (((m >> 2) & 7) << 4));
            *(unsigned short*)(bp)       = f2bf(t[j][0]);
            *(unsigned short*)(bp + 256) = f2bf(t[j][1]);
            *(unsigned short*)(bp + 512) = f2bf(t[j][2]);
            *(unsigned short*)(bp + 768) = f2bf(t[j][3]);
        }
    }

    // weight fragments (fp32 global -> bf16 regs), vectorized float4 loads
    bf16x8 wqf[4], wkf[4], wvf[4];
    #pragma unroll
    for (int ks = 0; ks < 4; ++ks) {
        const float4v* sq = (const float4v*)(Wq + c15 * 128 + ks * 32 + g * 8);
        const float4v* sk = (const float4v*)(Wk + c15 * 128 + ks * 32 + g * 8);
        const float4v* sv = (const float4v*)(Wv + (wv * 16 + c15) * 128 + ks * 32 + g * 8);
        float4v q0 = sq[0], q1 = sq[1];
        float4v k0 = sk[0], k1 = sk[1];
        float4v v0 = sv[0], v1 = sv[1];
        #pragma unroll
        for (int e = 0; e < 4; ++e) {
            wqf[ks][e] = (short)f2bf(q0[e]); wqf[ks][4 + e] = (short)f2bf(q1[e]);
            wkf[ks][e] = (short)f2bf(k0[e]); wkf[ks][4 + e] = (short)f2bf(k1[e]);
            wvf[ks][e] = (short)f2bf(v0[e]); wvf[ks][4 + e] = (short)f2bf(v1[e]);
        }
    }
    const float bqv = bq[c15], bkv = bk[c15];
    const f32x4 zacc = {0.f, 0.f, 0.f, 0.f};
    const bf16x8 zfrag = (bf16x8)(short)0;

    __syncthreads();   // B1: blkT staged

    // P1: qhat for this wave's 16 queries (tile qq*128 + wv*16), wave-local
    {
        f32x4 acc = zacc;
        int mrow = qq * 128 + wv * 16 + c15;
        int sw = ((mrow >> 2) & 7) << 4;
        #pragma unroll
        for (int ks = 0; ks < 4; ++ks) {
            bf16x8 af = *(const bf16x8*)(smem + ((mrow * 256 + ks * 64 + g * 16) ^ sw));
            acc = MFMA16(af, wqf[ks], acc);
        }
        #pragma unroll
        for (int r = 0; r < 4; ++r)
            *(unsigned short*)(smem + KOFF + wv * 2048 + (g * 4 + r) * 32 + 2 * c15) = f2bf(acc[r] + bqv);
    }
    bf16x8 qf = zfrag;
    if (g < 2) qf = *(const bf16x8*)(smem + KOFF + wv * 2048 + c15 * 32 + g * 16);

    // P2: Khat[mk][d] for this wave's 64 keys (overwrites own scratch slice)
    #pragma unroll
    for (int qi = 0; qi < 4; ++qi) {
        f32x4 acc = zacc;
        int mrow = wv * 64 + qi * 16 + c15;
        int sw = ((mrow >> 2) & 7) << 4;
        #pragma unroll
        for (int ks = 0; ks < 4; ++ks) {
            bf16x8 af = *(const bf16x8*)(smem + ((mrow * 256 + ks * 64 + g * 16) ^ sw));
            acc = MFMA16(af, wkf[ks], acc);
        }
        #pragma unroll
        for (int r = 0; r < 4; ++r) {
            int mk = wv * 64 + qi * 16 + g * 4 + r;
            *(unsigned short*)(smem + KOFF + mk * 32 + 2 * c15) = f2bf(acc[r] + bkv);
        }
    }

    // P3: Vhat in 4 chunks of 128 keys, in-place over consumed blkT rows
    for (int ck = 0; ck < 4; ++ck) {
        f32x4 vacc[8];
        #pragma unroll
        for (int mt = 0; mt < 8; ++mt) {
            vacc[mt] = zacc;
            int mrow = ck * 128 + mt * 16 + c15;
            int sw = ((mrow >> 2) & 7) << 4;
            #pragma unroll
            for (int ks = 0; ks < 4; ++ks) {
                bf16x8 bf = *(const bf16x8*)(smem + ((mrow * 256 + ks * 64 + g * 16) ^ sw));
                vacc[mt] = MFMA16(wvf[ks], bf, vacc[mt]);
            }
        }
        __syncthreads();
        #pragma unroll
        for (int mt = 0; mt < 8; ++mt) {
            #pragma unroll
            for (int r = 0; r < 4; ++r) {
                int c_out = wv * 16 + g * 4 + r;
                int mkl = mt * 16 + c15;
                *(unsigned short*)(smem + ck * 32768 + c_out * 256 +
                                   ((2 * mkl) ^ ((c_out & 7) << 4))) = f2bf(vacc[mt][r]);
            }
        }
    }
    __syncthreads();   // B3: Vhat + Khat visible

    // P4: barrier-free key-tile loop. O[16q][128c] per wave, in regs.
    f32x4 o[8];
    #pragma unroll
    for (int ci = 0; ci < 8; ++ci) o[ci] = zacc;
    float lsum = 0.f;

    for (int kt = 0; kt < 16; ++kt) {
        int mk0 = kt * 32;
        bf16x8 ka[2];
        #pragma unroll
        for (int ki = 0; ki < 2; ++ki) {
            bf16x8 v = zfrag;
            if (g < 2) v = *(const bf16x8*)(smem + KOFF + (mk0 + ki * 16 + c15) * 32 + g * 16);
            ka[ki] = v;
        }

        f32x4 s0 = MFMA16(ka[0], qf, zacc);
        f32x4 s1 = MFMA16(ka[1], qf, zacc);
        float e00 = __expf(s0[0]), e01 = __expf(s0[1]), e02 = __expf(s0[2]), e03 = __expf(s0[3]);
        float e10 = __expf(s1[0]), e11 = __expf(s1[1]), e12 = __expf(s1[2]), e13 = __expf(s1[3]);
        lsum += (e00 + e01) + (e02 + e03) + ((e10 + e11) + (e12 + e13));
        int wA0 = pkbf(e00, e01), wB0 = pkbf(e02, e03);
        int wA1 = pkbf(e10, e11), wB1 = pkbf(e12, e13);
        int src1 = ((2 * g) & 3) * 16 + c15;
        int src2 = ((2 * g + 1) & 3) * 16 + c15;
        int sA0a = __shfl(wA0, src1, 64), sA1a = __shfl(wA1, src1, 64);
        int sB0a = __shfl(wB0, src1, 64), sB1a = __shfl(wB1, src1, 64);
        int sA0b = __shfl(wA0, src2, 64), sA1b = __shfl(wA1, src2, 64);
        int sB0b = __shfl(wB0, src2, 64), sB1b = __shfl(wB1, src2, 64);
        bool k1 = (g >= 2);
        i32x4 uu = { k1 ? sA1a : sA0a, k1 ? sB1a : sB0a,
                     k1 ? sA1b : sA0b, k1 ? sB1b : sB0b };
        bf16x8 pa = __builtin_bit_cast(bf16x8, uu);

        int ckbase = (mk0 >> 7) * 32768;
        int mklb = (2 * (mk0 & 127)) + 16 * g;
        #pragma unroll
        for (int ci = 0; ci < 8; ++ci) {
            int c = ci * 16 + c15;
            bf16x8 vb = *(const bf16x8*)(smem + ckbase + c * 256 + (mklb ^ ((c & 7) << 4)));
            o[ci] = MFMA16(pa, vb, o[ci]);
        }
    }

    // softmax denominators for this wave's 16 queries
    {
        float l = lsum;
        l += __shfl_xor(l, 16, 64);
        l += __shfl_xor(l, 32, 64);
        if (g == 0)
            *(float*)(smem + LOFF + (wv * 16 + c15) * 4) = l;
    }

    __syncthreads();   // B4: Vhat/Khat reads done, safe to overwrite with O

    #pragma unroll
    for (int ci = 0; ci < 8; ++ci)
        #pragma unroll
        for (int r = 0; r < 4; ++r) {
            int nql = wv * 16 + g * 4 + r;           // 0..127
            int c = ci * 16 + c15;
            *(unsigned short*)(smem + c * 256 + ((2 * nql) ^ ((c & 7) << 4))) = f2bf(o[ci][r]);
        }
    __syncthreads();   // B5: O visible

    // epilogue: in-place RMW on out (out currently holds x from the memcpy):
    // out = gamma*(O/l + bv) + out. Lines are L2/L3-hot from the memcpy write;
    // the read brings the line, the store dirties it — no RFO, no x re-read.
    float gma = gamma[0];
    int q128 = tid & 127;                            // wg-local query
    int cb = tid >> 7;                               // channel block 0..3 (32 ch each)
    float invl = 1.0f / *(const float*)(smem + LOFF + q128 * 4);
    int nq = qq * 128 + q128;
    int vox = ((nq >> 6) << 12) + (((nq >> 3) & 7) << 6) + (nq & 7);
    int go = vbase + vox;
    #pragma unroll
    for (int b = 0; b < 4; ++b) {
        float xv[8];
        #pragma unroll
        for (int j = 0; j < 8; ++j) {
            int c = cb * 32 + b * 8 + j;
            xv[j] = out[c * 262144 + go];            // = x (copied), hot
        }
        #pragma unroll
        for (int j = 0; j < 8; ++j) {
            int c = cb * 32 + b * 8 + j;
            float ov = bf2f(*(const unsigned short*)(smem + c * 256 + ((2 * q128) ^ ((c & 7) << 4))));
            out[c * 262144 + go] = gma * (ov * invl + bv[c]) + xv[j];
        }
    }
}

extern "C" void kernel_launch(void* const* d_in, const int* in_sizes, int n_in,
                              void* d_out, int out_size, void* d_ws, size_t ws_size,
                              hipStream_t stream) {
    const float* x     = (const float*)d_in[0];
    const float* Wq    = (const float*)d_in[1];
    const float* bq    = (const float*)d_in[2];
    const float* Wk    = (const float*)d_in[3];
    const float* bk    = (const float*)d_in[4];
    const float* Wv    = (const float*)d_in[5];
    const float* bv    = (const float*)d_in[6];
    const float* gamma = (const float*)d_in[7];
    float* out = (float*)d_out;
    (void)in_sizes; (void)n_in; (void)out_size; (void)d_ws; (void)ws_size;

    // 1) SDMA copy: out = x everywhere (6.3 TB/s; shaders can't match this).
    hipMemcpyAsync(out, x, (size_t)out_size * sizeof(float),
                   hipMemcpyDeviceToDevice, stream);
    // 2) Diagonal attention; epilogue RMWs out in place (hot lines).
    battn_kernel<<<dim3(256), dim3(512), 0, stream>>>(x, Wq, bq, Wk, bk, Wv, bv, gamma, out);
}